// Round 4
// baseline (559.632 us; speedup 1.0000x reference)
//
#include <hip/hip_runtime.h>
#include <hip/hip_fp16.h>

#define DIN 128
#define BSH 7                 // log2(targets per bucket)
#define BSIZE 128             // targets per bucket
#define NBMAX 800             // max bucket count (N<=102400)
#define CAP 4480              // slots per bucket region (mean 4096, +6 sigma)
#define CHUNK 8192            // edges per place-WG

// ---------- K0: init per-bucket cursors ----------
__global__ __launch_bounds__(256) void init_kernel(int* __restrict__ cur, int NB) {
    int i = blockIdx.x * 256 + threadIdx.x;
    if (i < NB) cur[i] = i * CAP;
}

// ---------- K1: bucket the edges (LDS-staged, coalesced run writes) ----------
__global__ __launch_bounds__(256) void place_kernel(const int* __restrict__ row,
                                                    const int* __restrict__ col,
                                                    int* __restrict__ cur,
                                                    int* __restrict__ sp, int E, int NB) {
    __shared__ int pk[CHUNK];
    __shared__ unsigned short bkid[CHUNK];
    __shared__ int lcnt[NBMAX], lstart[NBMAX], gofs[NBMAX], lcur[NBMAX];
    __shared__ int sst[256];
    int t = threadIdx.x;
    int e0 = blockIdx.x * CHUNK;
    int cnt = min(CHUNK, E - e0);

    for (int i = t; i < NBMAX; i += 256) { lcnt[i] = 0; lcur[i] = 0; }
    __syncthreads();
    for (int i = t; i < cnt; i += 256)
        atomicAdd(&lcnt[col[e0 + i] >> BSH], 1);
    __syncthreads();
    int b4 = t * 4;
    int v0 = (b4 + 0 < NBMAX) ? lcnt[b4 + 0] : 0;
    int v1 = (b4 + 1 < NBMAX) ? lcnt[b4 + 1] : 0;
    int v2 = (b4 + 2 < NBMAX) ? lcnt[b4 + 2] : 0;
    int v3 = (b4 + 3 < NBMAX) ? lcnt[b4 + 3] : 0;
    int tot = v0 + v1 + v2 + v3;
    sst[t] = tot;
    __syncthreads();
    for (int d = 1; d < 256; d <<= 1) {
        int tmp = (t >= d) ? sst[t - d] : 0;
        __syncthreads();
        sst[t] += tmp;
        __syncthreads();
    }
    int ex = sst[t] - tot;
    if (b4 + 0 < NBMAX) lstart[b4 + 0] = ex;
    if (b4 + 1 < NBMAX) lstart[b4 + 1] = ex + v0;
    if (b4 + 2 < NBMAX) lstart[b4 + 2] = ex + v0 + v1;
    if (b4 + 3 < NBMAX) lstart[b4 + 3] = ex + v0 + v1 + v2;
    __syncthreads();
    for (int b = t; b < NB; b += 256) {
        int c = lcnt[b];
        int gb = c ? atomicAdd(&cur[b], c) : 0;
        gofs[b] = gb - lstart[b];
    }
    __syncthreads();
    for (int i = t; i < cnt; i += 256) {
        int r  = row[e0 + i];
        int cc = col[e0 + i];
        int b  = cc >> BSH;
        int rk = atomicAdd(&lcur[b], 1);
        int pos = lstart[b] + rk;
        pk[pos]   = ((cc & (BSIZE - 1)) << 17) | r;
        bkid[pos] = (unsigned short)b;
    }
    __syncthreads();
    for (int i = t; i < cnt; i += 256)
        sp[gofs[bkid[i]] + i] = pk[i];
}

// ---------- K2: per-bucket degree -> dis ----------
__global__ __launch_bounds__(256) void bdeg_kernel(const int* __restrict__ sp,
                                                   const int* __restrict__ cur,
                                                   float* __restrict__ dis, int N) {
    __shared__ int lcnt[BSIZE];
    int b = blockIdx.x;
    int t = threadIdx.x;
    int cntb = cur[b] - b * CAP;
    const int* src = sp + (size_t)b * CAP;
    if (t < BSIZE) lcnt[t] = 0;
    __syncthreads();
    for (int i = t; i < cntb; i += 256)
        atomicAdd(&lcnt[src[i] >> 17], 1);
    __syncthreads();
    if (t < BSIZE) {
        int gt = b * BSIZE + t;
        if (gt < N) dis[gt] = rsqrtf((float)lcnt[t] + 1.0f);
    }
}

// ---------- K3: hp = fp16( (x @ W1) * dis[n] ) ----------
__global__ __launch_bounds__(256) void xw1_kernel(const float* __restrict__ x,
                                                  const float* __restrict__ W1,
                                                  const float* __restrict__ dis,
                                                  __half* __restrict__ hp, int N) {
    __shared__ float ws[DIN * 16];
    __shared__ float xs[16 * 129];
    int base = blockIdx.x * 16;
    for (int i = threadIdx.x; i < DIN * 16; i += 256) ws[i] = W1[i];
    for (int i = threadIdx.x; i < 16 * DIN; i += 256) {
        int nd = i >> 7, d = i & 127;
        int n = base + nd;
        xs[nd * 129 + d] = (n < N) ? x[(size_t)n * DIN + d] : 0.0f;
    }
    __syncthreads();
    int nd = threadIdx.x >> 4;
    int k  = threadIdx.x & 15;
    int n  = base + nd;
    if (n >= N) return;
    const float* xr = xs + nd * 129;
    float acc = 0.0f;
    #pragma unroll
    for (int d = 0; d < DIN; d++) acc = fmaf(xr[d], ws[d * 16 + k], acc);
    hp[(size_t)n * 16 + k] = __float2half(acc * dis[n]);
}

// ---------- K4: fused per-bucket gather-1 + (relu,b1,@W2,*dis) -> gp ----------
__global__ __launch_bounds__(256) void bgather1_kernel(const int* __restrict__ sp,
                                                       const int* __restrict__ cur,
                                                       const float* __restrict__ dis,
                                                       const __half* __restrict__ hp,
                                                       const float* __restrict__ b1,
                                                       const float* __restrict__ W2,
                                                       float* __restrict__ gp, int N) {
    __shared__ int spk[CAP];
    __shared__ float a1loc[BSIZE * 16];
    int b = blockIdx.x;
    int t = threadIdx.x;
    int cntb = cur[b] - b * CAP;
    const int* src = sp + (size_t)b * CAP;
    for (int i = t; i < BSIZE * 16; i += 256) a1loc[i] = 0.0f;
    for (int i = t; i < cntb; i += 256) spk[i] = src[i];
    __syncthreads();

    int k    = t & 15;
    int slot = t >> 4;              // 16 edge slots
    for (int i0 = slot; i0 < cntb; i0 += 64) {
        float hv[4]; int lc[4]; int ok[4];
        #pragma unroll
        for (int u = 0; u < 4; u++) {
            int i = i0 + u * 16;
            ok[u] = (i < cntb);
            int v = ok[u] ? spk[i] : 0;
            int r = v & 0x1FFFF;
            lc[u] = v >> 17;
            hv[u] = ok[u] ? __half2float(hp[(size_t)r * 16 + k]) : 0.0f;
        }
        #pragma unroll
        for (int u = 0; u < 4; u++)
            if (ok[u]) atomicAdd(&a1loc[lc[u] * 16 + k], hv[u]);
    }
    __syncthreads();

    // epilogue: 2 threads per target (one per output class)
    int lt  = t >> 1;
    int cls = t & 1;
    int gt  = b * BSIZE + lt;
    if (gt < N) {
        float d = dis[gt];
        float g = 0.0f;
        #pragma unroll
        for (int kk = 0; kk < 16; kk++) {
            float self = __half2float(hp[(size_t)gt * 16 + kk]);
            float a = (a1loc[lt * 16 + kk] + self) * d + b1[kk];
            float v = fmaxf(a, 0.0f);
            g = fmaf(v, W2[kk * 2 + cls], g);
        }
        gp[(size_t)gt * 2 + cls] = g * d;
    }
}

// ---------- K5: fused per-bucket gather-2 + bias + log_softmax ----------
__global__ __launch_bounds__(256) void bgather2_kernel(const int* __restrict__ sp,
                                                       const int* __restrict__ cur,
                                                       const float* __restrict__ dis,
                                                       const float* __restrict__ gp,
                                                       const float* __restrict__ b2,
                                                       float* __restrict__ out, int N) {
    __shared__ float acc[BSIZE * 2];
    int b = blockIdx.x;
    int t = threadIdx.x;
    int cntb = cur[b] - b * CAP;
    const int* src = sp + (size_t)b * CAP;
    for (int i = t; i < BSIZE * 2; i += 256) acc[i] = 0.0f;
    __syncthreads();

    for (int i0 = t; i0 < cntb; i0 += 1024) {
        float2 gv[4]; int lc[4]; int ok[4];
        #pragma unroll
        for (int u = 0; u < 4; u++) {
            int i = i0 + u * 256;
            ok[u] = (i < cntb);
            int v = ok[u] ? src[i] : 0;
            int r = v & 0x1FFFF;
            lc[u] = v >> 17;
            gv[u] = ok[u] ? *(const float2*)(gp + (size_t)r * 2) : make_float2(0.f, 0.f);
        }
        #pragma unroll
        for (int u = 0; u < 4; u++) {
            if (ok[u]) {
                atomicAdd(&acc[lc[u] * 2 + 0], gv[u].x);
                atomicAdd(&acc[lc[u] * 2 + 1], gv[u].y);
            }
        }
    }
    __syncthreads();

    if (t < BSIZE) {
        int gt = b * BSIZE + t;
        if (gt < N) {
            float d = dis[gt];
            float2 self = *(const float2*)(gp + (size_t)gt * 2);
            float o0 = (acc[t * 2 + 0] + self.x) * d + b2[0];
            float o1 = (acc[t * 2 + 1] + self.y) * d + b2[1];
            float m = fmaxf(o0, o1);
            float lse = m + logf(expf(o0 - m) + expf(o1 - m));
            *(float2*)(out + (size_t)gt * 2) = make_float2(o0 - lse, o1 - lse);
        }
    }
}

extern "C" void kernel_launch(void* const* d_in, const int* in_sizes, int n_in,
                              void* d_out, int out_size, void* d_ws, size_t ws_size,
                              hipStream_t stream) {
    const float* x  = (const float*)d_in[0];
    const int*   ei = (const int*)d_in[1];
    const float* W1 = (const float*)d_in[2];
    const float* b1 = (const float*)d_in[3];
    const float* W2 = (const float*)d_in[4];
    const float* b2 = (const float*)d_in[5];
    float* out = (float*)d_out;

    const int N = in_sizes[0] / DIN;          // 100000
    const int E = in_sizes[1] / 2;            // 3200000
    const int* row = ei;                      // sources
    const int* col = ei + E;                  // targets
    const int NB = (N + BSIZE - 1) / BSIZE;   // 782

    // ws layout (4B units): cur[NBMAX] | dis[N] | sp[NB*CAP] | hp(half)[16N] | gp[2N]
    int*    cur = (int*)d_ws;
    float*  dis = (float*)(cur + NBMAX);
    int*    sp  = (int*)(dis + N);
    __half* hp  = (__half*)(sp + (size_t)NB * CAP);
    float*  gp  = (float*)(hp + (size_t)N * 16);

    init_kernel <<<(NB + 255) / 256, 256, 0, stream>>>(cur, NB);
    place_kernel<<<(E + CHUNK - 1) / CHUNK, 256, 0, stream>>>(row, col, cur, sp, E, NB);
    bdeg_kernel <<<NB, 256, 0, stream>>>(sp, cur, dis, N);
    xw1_kernel  <<<(N + 15) / 16, 256, 0, stream>>>(x, W1, dis, hp, N);
    bgather1_kernel<<<NB, 256, 0, stream>>>(sp, cur, dis, hp, b1, W2, gp, N);
    bgather2_kernel<<<NB, 256, 0, stream>>>(sp, cur, dis, gp, b2, out, N);
}

// Round 5
// 259.908 us; speedup vs baseline: 2.1532x; 2.1532x over previous
//
#include <hip/hip_runtime.h>
#include <hip/hip_fp16.h>

#define DIN 128
#define BSH 7                 // log2(targets per bucket)
#define BSIZE 128             // targets per bucket
#define NBMAX 800             // max bucket count (N<=102400)
#define CAP 4480              // slots per bucket region (mean 4096, +6 sigma)
#define CHUNK 8192            // edges per place-WG

// ---------- K0: init per-bucket cursors ----------
__global__ __launch_bounds__(256) void init_kernel(int* __restrict__ cur, int NB) {
    int i = blockIdx.x * 256 + threadIdx.x;
    if (i < NB) cur[i] = i * CAP;
}

// ---------- K1: bucket the edges (LDS-staged, coalesced run writes) ----------
__global__ __launch_bounds__(256) void place_kernel(const int* __restrict__ row,
                                                    const int* __restrict__ col,
                                                    int* __restrict__ cur,
                                                    int* __restrict__ sp, int E, int NB) {
    __shared__ int pk[CHUNK];
    __shared__ unsigned short bkid[CHUNK];
    __shared__ int lcnt[NBMAX], lstart[NBMAX], gofs[NBMAX], lcur[NBMAX];
    __shared__ int sst[256];
    int t = threadIdx.x;
    int e0 = blockIdx.x * CHUNK;
    int cnt = min(CHUNK, E - e0);

    for (int i = t; i < NBMAX; i += 256) { lcnt[i] = 0; lcur[i] = 0; }
    __syncthreads();
    for (int i = t; i < cnt; i += 256)
        atomicAdd(&lcnt[col[e0 + i] >> BSH], 1);
    __syncthreads();
    int b4 = t * 4;
    int v0 = (b4 + 0 < NBMAX) ? lcnt[b4 + 0] : 0;
    int v1 = (b4 + 1 < NBMAX) ? lcnt[b4 + 1] : 0;
    int v2 = (b4 + 2 < NBMAX) ? lcnt[b4 + 2] : 0;
    int v3 = (b4 + 3 < NBMAX) ? lcnt[b4 + 3] : 0;
    int tot = v0 + v1 + v2 + v3;
    sst[t] = tot;
    __syncthreads();
    for (int d = 1; d < 256; d <<= 1) {
        int tmp = (t >= d) ? sst[t - d] : 0;
        __syncthreads();
        sst[t] += tmp;
        __syncthreads();
    }
    int ex = sst[t] - tot;
    if (b4 + 0 < NBMAX) lstart[b4 + 0] = ex;
    if (b4 + 1 < NBMAX) lstart[b4 + 1] = ex + v0;
    if (b4 + 2 < NBMAX) lstart[b4 + 2] = ex + v0 + v1;
    if (b4 + 3 < NBMAX) lstart[b4 + 3] = ex + v0 + v1 + v2;
    __syncthreads();
    for (int b = t; b < NB; b += 256) {
        int c = lcnt[b];
        int gb = c ? atomicAdd(&cur[b], c) : 0;
        gofs[b] = gb - lstart[b];
    }
    __syncthreads();
    for (int i = t; i < cnt; i += 256) {
        int r  = row[e0 + i];
        int cc = col[e0 + i];
        int b  = cc >> BSH;
        int rk = atomicAdd(&lcur[b], 1);
        int pos = lstart[b] + rk;
        pk[pos]   = ((cc & (BSIZE - 1)) << 17) | r;
        bkid[pos] = (unsigned short)b;
    }
    __syncthreads();
    for (int i = t; i < cnt; i += 256)
        sp[gofs[bkid[i]] + i] = pk[i];
}

// ---------- K2: exclusive scan of bucket counts -> compact CSR bases ----------
__global__ __launch_bounds__(1024) void bscan_kernel(const int* __restrict__ cur,
                                                     int* __restrict__ bbase, int NB) {
    __shared__ int s[1024];
    int t = threadIdx.x;
    int v = (t < NB) ? (cur[t] - t * CAP) : 0;
    s[t] = v;
    __syncthreads();
    for (int d = 1; d < 1024; d <<= 1) {
        int tmp = (t >= d) ? s[t - d] : 0;
        __syncthreads();
        s[t] += tmp;
        __syncthreads();
    }
    if (t < NB) bbase[t] = s[t] - v;
    if (t == NB - 1) bbase[NB] = s[t];   // == E
}

// ---------- K3: per-bucket LDS counting sort; emit srt/off/dis ----------
__global__ __launch_bounds__(256) void bsort_kernel(const int* __restrict__ sp,
                                                    const int* __restrict__ bbase,
                                                    int* __restrict__ srt,
                                                    int* __restrict__ off,
                                                    float* __restrict__ dis, int N) {
    __shared__ int spk[CAP];
    __shared__ int ss[CAP];
    __shared__ int lcnt[BSIZE], lstart[BSIZE], lcur[BSIZE], sc[BSIZE];
    int b = blockIdx.x;
    int t = threadIdx.x;
    int base = bbase[b];
    int cntb = bbase[b + 1] - base;
    const int* src = sp + (size_t)b * CAP;
    if (t < BSIZE) { lcnt[t] = 0; lcur[t] = 0; }
    __syncthreads();
    for (int i = t; i < cntb; i += 256) {
        int v = src[i];
        spk[i] = v;
        atomicAdd(&lcnt[v >> 17], 1);
    }
    __syncthreads();
    int v = (t < BSIZE) ? lcnt[t] : 0;
    if (t < BSIZE) sc[t] = v;
    __syncthreads();
    for (int d = 1; d < BSIZE; d <<= 1) {
        int tmp = (t < BSIZE && t >= d) ? sc[t - d] : 0;
        __syncthreads();
        if (t < BSIZE) sc[t] += tmp;
        __syncthreads();
    }
    if (t < BSIZE) lstart[t] = sc[t] - v;
    __syncthreads();
    for (int i = t; i < cntb; i += 256) {
        int vv = spk[i];
        int lt = vv >> 17;
        int rk = atomicAdd(&lcur[lt], 1);
        ss[lstart[lt] + rk] = vv & 0x1FFFF;
    }
    __syncthreads();
    for (int i = t; i < cntb; i += 256) srt[base + i] = ss[i];
    if (t < BSIZE) {
        int gt = b * BSIZE + t;
        if (gt < N) {
            off[gt] = base + lstart[t];
            dis[gt] = rsqrtf((float)lcnt[t] + 1.0f);
        }
    }
}

// ---------- K4: hp = fp16( (x @ W1) * dis[n] ) ----------
__global__ __launch_bounds__(256) void xw1_kernel(const float* __restrict__ x,
                                                  const float* __restrict__ W1,
                                                  const float* __restrict__ dis,
                                                  __half* __restrict__ hp, int N) {
    __shared__ float ws[DIN * 16];
    __shared__ float xs[16 * 129];
    int base = blockIdx.x * 16;
    for (int i = threadIdx.x; i < DIN * 16; i += 256) ws[i] = W1[i];
    for (int i = threadIdx.x; i < 16 * DIN; i += 256) {
        int nd = i >> 7, d = i & 127;
        int n = base + nd;
        xs[nd * 129 + d] = (n < N) ? x[(size_t)n * DIN + d] : 0.0f;
    }
    __syncthreads();
    int nd = threadIdx.x >> 4;
    int k  = threadIdx.x & 15;
    int n  = base + nd;
    if (n >= N) return;
    const float* xr = xs + nd * 129;
    float acc = 0.0f;
    #pragma unroll
    for (int d = 0; d < DIN; d++) acc = fmaf(xr[d], ws[d * 16 + k], acc);
    hp[(size_t)n * 16 + k] = __float2half(acc * dis[n]);
}

// ---------- K5: CSR gather-1 (8 lanes/target, half2) + fused relu/b1/@W2/*dis ----------
__global__ __launch_bounds__(256) void g1_kernel(const int* __restrict__ srt,
                                                 const int* __restrict__ off,
                                                 const float* __restrict__ dis,
                                                 const __half2* __restrict__ hp2,
                                                 const float* __restrict__ b1,
                                                 const float* __restrict__ W2,
                                                 float* __restrict__ gp, int N, int E) {
    int t = blockIdx.x * 256 + threadIdx.x;
    int c  = t >> 3;
    int k2 = t & 7;
    if (c >= N) return;
    int j0 = off[c];
    int j1 = (c == N - 1) ? E : off[c + 1];
    float2 acc = __half22float2(hp2[(size_t)c * 8 + k2]);   // self-loop
    for (int j = j0; j < j1; j++) {
        int r = srt[j];
        float2 hv = __half22float2(hp2[(size_t)r * 8 + k2]);
        acc.x += hv.x;
        acc.y += hv.y;
    }
    float d = dis[c];
    int k0 = k2 * 2;
    float v0 = fmaxf(fmaf(acc.x, d, b1[k0 + 0]), 0.0f);
    float v1 = fmaxf(fmaf(acc.y, d, b1[k0 + 1]), 0.0f);
    float p0 = v0 * W2[k0 * 2 + 0] + v1 * W2[k0 * 2 + 2];
    float p1 = v0 * W2[k0 * 2 + 1] + v1 * W2[k0 * 2 + 3];
    p0 += __shfl_xor(p0, 1); p1 += __shfl_xor(p1, 1);
    p0 += __shfl_xor(p0, 2); p1 += __shfl_xor(p1, 2);
    p0 += __shfl_xor(p0, 4); p1 += __shfl_xor(p1, 4);
    if (k2 == 0) *(float2*)(gp + (size_t)c * 2) = make_float2(p0 * d, p1 * d);
}

// ---------- K6: CSR gather-2 + bias + log_softmax ----------
__global__ __launch_bounds__(256) void g2_kernel(const int* __restrict__ srt,
                                                 const int* __restrict__ off,
                                                 const float* __restrict__ dis,
                                                 const float* __restrict__ gp,
                                                 const float* __restrict__ b2,
                                                 float* __restrict__ out, int N, int E) {
    int c = blockIdx.x * 256 + threadIdx.x;
    if (c >= N) return;
    int j0 = off[c];
    int j1 = (c == N - 1) ? E : off[c + 1];
    float2 self = *(const float2*)(gp + (size_t)c * 2);
    float a0 = self.x, a1v = self.y;
    for (int j = j0; j < j1; j++) {
        int r = srt[j];
        float2 gv = *(const float2*)(gp + (size_t)r * 2);
        a0 += gv.x;
        a1v += gv.y;
    }
    float d = dis[c];
    float o0 = a0 * d + b2[0];
    float o1 = a1v * d + b2[1];
    float m = fmaxf(o0, o1);
    float lse = m + logf(expf(o0 - m) + expf(o1 - m));
    *(float2*)(out + (size_t)c * 2) = make_float2(o0 - lse, o1 - lse);
}

extern "C" void kernel_launch(void* const* d_in, const int* in_sizes, int n_in,
                              void* d_out, int out_size, void* d_ws, size_t ws_size,
                              hipStream_t stream) {
    const float* x  = (const float*)d_in[0];
    const int*   ei = (const int*)d_in[1];
    const float* W1 = (const float*)d_in[2];
    const float* b1 = (const float*)d_in[3];
    const float* W2 = (const float*)d_in[4];
    const float* b2 = (const float*)d_in[5];
    float* out = (float*)d_out;

    const int N = in_sizes[0] / DIN;          // 100000
    const int E = in_sizes[1] / 2;            // 3200000
    const int* row = ei;                      // sources
    const int* col = ei + E;                  // targets
    const int NB = (N + BSIZE - 1) / BSIZE;   // 782

    // ws layout (4B units): cur[NBMAX] | bbase[NBMAX+1] | dis[N] | off[N] | srt[E] |
    //                       sp[NB*CAP]  (sp dead after bsort; aliased by hp(half)[16N] | gp[2N])
    int*    cur   = (int*)d_ws;
    int*    bbase = cur + NBMAX;
    float*  dis   = (float*)(bbase + NBMAX + 1);
    int*    off   = (int*)(dis + N);
    int*    srt   = off + N;
    int*    sp    = srt + E;
    __half* hp    = (__half*)sp;
    float*  gp    = (float*)(hp + (size_t)N * 16);

    init_kernel <<<(NB + 255) / 256, 256, 0, stream>>>(cur, NB);
    place_kernel<<<(E + CHUNK - 1) / CHUNK, 256, 0, stream>>>(row, col, cur, sp, E, NB);
    bscan_kernel<<<1, 1024, 0, stream>>>(cur, bbase, NB);
    bsort_kernel<<<NB, 256, 0, stream>>>(sp, bbase, srt, off, dis, N);
    xw1_kernel  <<<(N + 15) / 16, 256, 0, stream>>>(x, W1, dis, hp, N);
    g1_kernel   <<<(int)(((size_t)N * 8 + 255) / 256), 256, 0, stream>>>(srt, off, dis, (const __half2*)hp, b1, W2, gp, N, E);
    g2_kernel   <<<(N + 255) / 256, 256, 0, stream>>>(srt, off, dis, gp, b2, out, N, E);
}

// Round 6
// 254.991 us; speedup vs baseline: 2.1947x; 1.0193x over previous
//
#include <hip/hip_runtime.h>
#include <hip/hip_fp16.h>

#define DIN 128
#define BSH 7                 // log2(targets per bucket)
#define BSIZE 128             // targets per bucket
#define NBMAX 800             // max bucket count (N<=102400)
#define CAP 4480              // slots per bucket region (mean 4096, +6 sigma)
#define CHUNK 4096            // edges per place-WG (38KB LDS -> 4 WG/CU)

// ---------- K0: init per-bucket cursors ----------
__global__ __launch_bounds__(256) void init_kernel(int* __restrict__ cur, int NB) {
    int i = blockIdx.x * 256 + threadIdx.x;
    if (i < NB) cur[i] = i * CAP;
}

// ---------- K1: bucket the edges (LDS-staged, coalesced run writes) ----------
__global__ __launch_bounds__(256) void place_kernel(const int* __restrict__ row,
                                                    const int* __restrict__ col,
                                                    int* __restrict__ cur,
                                                    int* __restrict__ sp, int E, int NB) {
    __shared__ int pk[CHUNK];
    __shared__ unsigned short bkid[CHUNK];
    __shared__ int lcnt[NBMAX], lstart[NBMAX], gofs[NBMAX], lcur[NBMAX];
    __shared__ int sst[256];
    int t = threadIdx.x;
    int e0 = blockIdx.x * CHUNK;
    int cnt = min(CHUNK, E - e0);

    for (int i = t; i < NBMAX; i += 256) { lcnt[i] = 0; lcur[i] = 0; }
    __syncthreads();
    for (int i = t; i < cnt; i += 256)
        atomicAdd(&lcnt[col[e0 + i] >> BSH], 1);
    __syncthreads();
    int b4 = t * 4;
    int v0 = (b4 + 0 < NBMAX) ? lcnt[b4 + 0] : 0;
    int v1 = (b4 + 1 < NBMAX) ? lcnt[b4 + 1] : 0;
    int v2 = (b4 + 2 < NBMAX) ? lcnt[b4 + 2] : 0;
    int v3 = (b4 + 3 < NBMAX) ? lcnt[b4 + 3] : 0;
    int tot = v0 + v1 + v2 + v3;
    sst[t] = tot;
    __syncthreads();
    for (int d = 1; d < 256; d <<= 1) {
        int tmp = (t >= d) ? sst[t - d] : 0;
        __syncthreads();
        sst[t] += tmp;
        __syncthreads();
    }
    int ex = sst[t] - tot;
    if (b4 + 0 < NBMAX) lstart[b4 + 0] = ex;
    if (b4 + 1 < NBMAX) lstart[b4 + 1] = ex + v0;
    if (b4 + 2 < NBMAX) lstart[b4 + 2] = ex + v0 + v1;
    if (b4 + 3 < NBMAX) lstart[b4 + 3] = ex + v0 + v1 + v2;
    __syncthreads();
    for (int b = t; b < NB; b += 256) {
        int c = lcnt[b];
        int gb = c ? atomicAdd(&cur[b], c) : 0;
        gofs[b] = gb - lstart[b];
    }
    __syncthreads();
    for (int i = t; i < cnt; i += 256) {
        int r  = row[e0 + i];
        int cc = col[e0 + i];
        int b  = cc >> BSH;
        int rk = atomicAdd(&lcur[b], 1);
        int pos = lstart[b] + rk;
        pk[pos]   = ((cc & (BSIZE - 1)) << 17) | r;
        bkid[pos] = (unsigned short)b;
    }
    __syncthreads();
    for (int i = t; i < cnt; i += 256)
        sp[gofs[bkid[i]] + i] = pk[i];
}

// ---------- K2: per-bucket degree -> dis (needed by xw1 before bsg1) ----------
__global__ __launch_bounds__(256) void bdeg_kernel(const int* __restrict__ sp,
                                                   const int* __restrict__ cur,
                                                   float* __restrict__ dis, int N) {
    __shared__ int lcnt[BSIZE];
    int b = blockIdx.x;
    int t = threadIdx.x;
    int cntb = cur[b] - b * CAP;
    const int* src = sp + (size_t)b * CAP;
    if (t < BSIZE) lcnt[t] = 0;
    __syncthreads();
    for (int i = t; i < cntb; i += 256)
        atomicAdd(&lcnt[src[i] >> 17], 1);
    __syncthreads();
    if (t < BSIZE) {
        int gt = b * BSIZE + t;
        if (gt < N) dis[gt] = rsqrtf((float)lcnt[t] + 1.0f);
    }
}

// ---------- K3: exclusive scan of bucket counts -> compact CSR bases ----------
__global__ __launch_bounds__(1024) void bscan_kernel(const int* __restrict__ cur,
                                                     int* __restrict__ bbase, int NB) {
    __shared__ int s[1024];
    int t = threadIdx.x;
    int v = (t < NB) ? (cur[t] - t * CAP) : 0;
    s[t] = v;
    __syncthreads();
    for (int d = 1; d < 1024; d <<= 1) {
        int tmp = (t >= d) ? s[t - d] : 0;
        __syncthreads();
        s[t] += tmp;
        __syncthreads();
    }
    if (t < NB) bbase[t] = s[t] - v;
    if (t == NB - 1) bbase[NB] = s[t];   // == E
}

// ---------- K4: hp = fp16( (x @ W1) * dis[n] ) ----------
__global__ __launch_bounds__(256) void xw1_kernel(const float* __restrict__ x,
                                                  const float* __restrict__ W1,
                                                  const float* __restrict__ dis,
                                                  __half* __restrict__ hp, int N) {
    __shared__ float ws[DIN * 16];
    __shared__ float xs[16 * 129];
    int base = blockIdx.x * 16;
    for (int i = threadIdx.x; i < DIN * 16; i += 256) ws[i] = W1[i];
    for (int i = threadIdx.x; i < 16 * DIN; i += 256) {
        int nd = i >> 7, d = i & 127;
        int n = base + nd;
        xs[nd * 129 + d] = (n < N) ? x[(size_t)n * DIN + d] : 0.0f;
    }
    __syncthreads();
    int nd = threadIdx.x >> 4;
    int k  = threadIdx.x & 15;
    int n  = base + nd;
    if (n >= N) return;
    const float* xr = xs + nd * 129;
    float acc = 0.0f;
    #pragma unroll
    for (int d = 0; d < DIN; d++) acc = fmaf(xr[d], ws[d * 16 + k], acc);
    hp[(size_t)n * 16 + k] = __float2half(acc * dis[n]);
}

// ---------- K5: fused per-bucket counting sort + gather-1 + relu/b1/@W2/*dis ----------
__global__ __launch_bounds__(256) void bsg1_kernel(const int* __restrict__ sp,
                                                   const int* __restrict__ bbase,
                                                   const float* __restrict__ dis,
                                                   const __half2* __restrict__ hp2,
                                                   const float* __restrict__ b1,
                                                   const float* __restrict__ W2,
                                                   int* __restrict__ srt,
                                                   int* __restrict__ off,
                                                   float* __restrict__ gp, int N) {
    __shared__ int spk[CAP];
    __shared__ int ss[CAP];
    __shared__ int lcnt[BSIZE], lstart[BSIZE], lcur[BSIZE], sc[BSIZE];
    int b = blockIdx.x;
    int t = threadIdx.x;
    int base = bbase[b];
    int cntb = bbase[b + 1] - base;
    const int* src = sp + (size_t)b * CAP;
    if (t < BSIZE) { lcnt[t] = 0; lcur[t] = 0; }
    __syncthreads();
    for (int i = t; i < cntb; i += 256) {
        int v = src[i];
        spk[i] = v;
        atomicAdd(&lcnt[v >> 17], 1);
    }
    __syncthreads();
    int v = (t < BSIZE) ? lcnt[t] : 0;
    if (t < BSIZE) sc[t] = v;
    __syncthreads();
    for (int d = 1; d < BSIZE; d <<= 1) {
        int tmp = (t < BSIZE && t >= d) ? sc[t - d] : 0;
        __syncthreads();
        if (t < BSIZE) sc[t] += tmp;
        __syncthreads();
    }
    if (t < BSIZE) lstart[t] = sc[t] - v;
    __syncthreads();
    for (int i = t; i < cntb; i += 256) {
        int vv = spk[i];
        int lt = vv >> 17;
        int rk = atomicAdd(&lcur[lt], 1);
        ss[lstart[lt] + rk] = vv & 0x1FFFF;
    }
    __syncthreads();
    // emit srt/off for g2 (coalesced)
    for (int i = t; i < cntb; i += 256) srt[base + i] = ss[i];
    if (t < BSIZE) {
        int gt = b * BSIZE + t;
        if (gt < N) off[gt] = base + lstart[t];
    }
    // gather + epilogue: 4 rounds of 32 targets x 8 lanes (ss reads are LDS broadcasts)
    int k2  = t & 7;
    int ltg = t >> 3;            // 0..31
    #pragma unroll
    for (int r4 = 0; r4 < 4; r4++) {
        int lt = r4 * 32 + ltg;
        int gt = b * BSIZE + lt;
        if (gt < N) {
            int j0 = lstart[lt];
            int j1 = j0 + lcnt[lt];
            float2 acc = __half22float2(hp2[(size_t)gt * 8 + k2]);  // self-loop
            for (int j = j0; j < j1; j++) {
                int r = ss[j];
                float2 hv = __half22float2(hp2[(size_t)r * 8 + k2]);
                acc.x += hv.x;
                acc.y += hv.y;
            }
            float d = dis[gt];
            int k0 = k2 * 2;
            float v0 = fmaxf(fmaf(acc.x, d, b1[k0 + 0]), 0.0f);
            float v1 = fmaxf(fmaf(acc.y, d, b1[k0 + 1]), 0.0f);
            float p0 = v0 * W2[k0 * 2 + 0] + v1 * W2[k0 * 2 + 2];
            float p1 = v0 * W2[k0 * 2 + 1] + v1 * W2[k0 * 2 + 3];
            p0 += __shfl_xor(p0, 1); p1 += __shfl_xor(p1, 1);
            p0 += __shfl_xor(p0, 2); p1 += __shfl_xor(p1, 2);
            p0 += __shfl_xor(p0, 4); p1 += __shfl_xor(p1, 4);
            if (k2 == 0) *(float2*)(gp + (size_t)gt * 2) = make_float2(p0 * d, p1 * d);
        }
    }
}

// ---------- K6: CSR gather-2 (4 lanes/target) + bias + log_softmax ----------
__global__ __launch_bounds__(256) void g2_kernel(const int* __restrict__ srt,
                                                 const int* __restrict__ off,
                                                 const float* __restrict__ dis,
                                                 const float* __restrict__ gp,
                                                 const float* __restrict__ b2,
                                                 float* __restrict__ out, int N, int E) {
    int t = blockIdx.x * 256 + threadIdx.x;
    int c    = t >> 2;
    int slot = t & 3;
    if (c >= N) return;
    int j0 = off[c];
    int j1 = (c == N - 1) ? E : off[c + 1];
    float a0 = 0.0f, a1v = 0.0f;
    for (int j = j0 + slot; j < j1; j += 4) {
        int r = srt[j];
        float2 gv = *(const float2*)(gp + (size_t)r * 2);
        a0  += gv.x;
        a1v += gv.y;
    }
    a0 += __shfl_xor(a0, 1); a1v += __shfl_xor(a1v, 1);
    a0 += __shfl_xor(a0, 2); a1v += __shfl_xor(a1v, 2);
    if (slot == 0) {
        float2 self = *(const float2*)(gp + (size_t)c * 2);
        float d = dis[c];
        float o0 = (a0  + self.x) * d + b2[0];
        float o1 = (a1v + self.y) * d + b2[1];
        float m = fmaxf(o0, o1);
        float lse = m + logf(expf(o0 - m) + expf(o1 - m));
        *(float2*)(out + (size_t)c * 2) = make_float2(o0 - lse, o1 - lse);
    }
}

extern "C" void kernel_launch(void* const* d_in, const int* in_sizes, int n_in,
                              void* d_out, int out_size, void* d_ws, size_t ws_size,
                              hipStream_t stream) {
    const float* x  = (const float*)d_in[0];
    const int*   ei = (const int*)d_in[1];
    const float* W1 = (const float*)d_in[2];
    const float* b1 = (const float*)d_in[3];
    const float* W2 = (const float*)d_in[4];
    const float* b2 = (const float*)d_in[5];
    float* out = (float*)d_out;

    const int N = in_sizes[0] / DIN;          // 100000
    const int E = in_sizes[1] / 2;            // 3200000
    const int* row = ei;                      // sources
    const int* col = ei + E;                  // targets
    const int NB = (N + BSIZE - 1) / BSIZE;   // 782

    // ws layout (4B units): cur[NBMAX] | bbase[NBMAX+1] | dis[N] | off[N] | srt[E] |
    //                       sp[NB*CAP] | hp(half)[16N] | gp[2N]   (~32 MB total)
    int*    cur   = (int*)d_ws;
    int*    bbase = cur + NBMAX;
    float*  dis   = (float*)(bbase + NBMAX + 1);
    int*    off   = (int*)(dis + N);
    int*    srt   = off + N;
    int*    sp    = srt + E;
    __half* hp    = (__half*)(sp + (size_t)NB * CAP);
    float*  gp    = (float*)(hp + (size_t)N * 16);

    init_kernel <<<(NB + 255) / 256, 256, 0, stream>>>(cur, NB);
    place_kernel<<<(E + CHUNK - 1) / CHUNK, 256, 0, stream>>>(row, col, cur, sp, E, NB);
    bdeg_kernel <<<NB, 256, 0, stream>>>(sp, cur, dis, N);
    bscan_kernel<<<1, 1024, 0, stream>>>(cur, bbase, NB);
    xw1_kernel  <<<(N + 15) / 16, 256, 0, stream>>>(x, W1, dis, hp, N);
    bsg1_kernel <<<NB, 256, 0, stream>>>(sp, bbase, dis, (const __half2*)hp, b1, W2, srt, off, gp, N);
    g2_kernel   <<<(int)(((size_t)N * 4 + 255) / 256), 256, 0, stream>>>(srt, off, dis, gp, b2, out, N, E);
}

// Round 7
// 215.235 us; speedup vs baseline: 2.6001x; 1.1847x over previous
//
#include <hip/hip_runtime.h>
#include <hip/hip_fp16.h>

#define DIN 128
#define BSH 7                 // log2(targets per bucket)
#define BSIZE 128             // targets per bucket
#define NBMAX 800             // max bucket count (N<=102400)
#define CAP 4480              // slots per bucket region (mean 4096, +6 sigma)
#define CHUNK 8192            // edges per place-WG (longer runs -> better write coalescing)

// ---------- K0: init per-bucket cursors ----------
__global__ __launch_bounds__(256) void init_kernel(int* __restrict__ cur, int NB) {
    int i = blockIdx.x * 256 + threadIdx.x;
    if (i < NB) cur[i] = i * CAP;
}

// ---------- K1: bucket the edges (LDS-staged, coalesced run writes) ----------
__global__ __launch_bounds__(256) void place_kernel(const int* __restrict__ row,
                                                    const int* __restrict__ col,
                                                    int* __restrict__ cur,
                                                    int* __restrict__ sp, int E, int NB) {
    __shared__ int pk[CHUNK];
    __shared__ unsigned short bkid[CHUNK];
    __shared__ int lcnt[NBMAX], lstart[NBMAX], gofs[NBMAX], lcur[NBMAX];
    __shared__ int sst[256];
    int t = threadIdx.x;
    int e0 = blockIdx.x * CHUNK;
    int cnt = min(CHUNK, E - e0);

    for (int i = t; i < NBMAX; i += 256) { lcnt[i] = 0; lcur[i] = 0; }
    __syncthreads();
    for (int i = t; i < cnt; i += 256)
        atomicAdd(&lcnt[col[e0 + i] >> BSH], 1);
    __syncthreads();
    int b4 = t * 4;
    int v0 = (b4 + 0 < NBMAX) ? lcnt[b4 + 0] : 0;
    int v1 = (b4 + 1 < NBMAX) ? lcnt[b4 + 1] : 0;
    int v2 = (b4 + 2 < NBMAX) ? lcnt[b4 + 2] : 0;
    int v3 = (b4 + 3 < NBMAX) ? lcnt[b4 + 3] : 0;
    int tot = v0 + v1 + v2 + v3;
    sst[t] = tot;
    __syncthreads();
    for (int d = 1; d < 256; d <<= 1) {
        int tmp = (t >= d) ? sst[t - d] : 0;
        __syncthreads();
        sst[t] += tmp;
        __syncthreads();
    }
    int ex = sst[t] - tot;
    if (b4 + 0 < NBMAX) lstart[b4 + 0] = ex;
    if (b4 + 1 < NBMAX) lstart[b4 + 1] = ex + v0;
    if (b4 + 2 < NBMAX) lstart[b4 + 2] = ex + v0 + v1;
    if (b4 + 3 < NBMAX) lstart[b4 + 3] = ex + v0 + v1 + v2;
    __syncthreads();
    for (int b = t; b < NB; b += 256) {
        int c = lcnt[b];
        int gb = c ? atomicAdd(&cur[b], c) : 0;
        gofs[b] = gb - lstart[b];
    }
    __syncthreads();
    for (int i = t; i < cnt; i += 256) {
        int r  = row[e0 + i];
        int cc = col[e0 + i];
        int b  = cc >> BSH;
        int rk = atomicAdd(&lcur[b], 1);
        int pos = lstart[b] + rk;
        pk[pos]   = ((cc & (BSIZE - 1)) << 17) | r;
        bkid[pos] = (unsigned short)b;
    }
    __syncthreads();
    for (int i = t; i < cnt; i += 256)
        sp[gofs[bkid[i]] + i] = pk[i];
}

// ---------- K2: per-bucket degree -> dis (int4 loads) ----------
__global__ __launch_bounds__(256) void bdeg_kernel(const int* __restrict__ sp,
                                                   const int* __restrict__ cur,
                                                   float* __restrict__ dis, int N) {
    __shared__ int lcnt[BSIZE];
    int b = blockIdx.x;
    int t = threadIdx.x;
    int cntb = cur[b] - b * CAP;
    const int* src = sp + (size_t)b * CAP;
    if (t < BSIZE) lcnt[t] = 0;
    __syncthreads();
    int n4 = cntb >> 2;
    const int4* src4 = (const int4*)src;
    for (int i = t; i < n4; i += 256) {
        int4 v = src4[i];
        atomicAdd(&lcnt[v.x >> 17], 1);
        atomicAdd(&lcnt[v.y >> 17], 1);
        atomicAdd(&lcnt[v.z >> 17], 1);
        atomicAdd(&lcnt[v.w >> 17], 1);
    }
    for (int i = (n4 << 2) + t; i < cntb; i += 256)
        atomicAdd(&lcnt[src[i] >> 17], 1);
    __syncthreads();
    if (t < BSIZE) {
        int gt = b * BSIZE + t;
        if (gt < N) dis[gt] = rsqrtf((float)lcnt[t] + 1.0f);
    }
}

// ---------- K3: exclusive scan of bucket counts -> compact CSR bases ----------
__global__ __launch_bounds__(1024) void bscan_kernel(const int* __restrict__ cur,
                                                     int* __restrict__ bbase, int NB) {
    __shared__ int s[1024];
    int t = threadIdx.x;
    int v = (t < NB) ? (cur[t] - t * CAP) : 0;
    s[t] = v;
    __syncthreads();
    for (int d = 1; d < 1024; d <<= 1) {
        int tmp = (t >= d) ? s[t - d] : 0;
        __syncthreads();
        s[t] += tmp;
        __syncthreads();
    }
    if (t < NB) bbase[t] = s[t] - v;
    if (t == NB - 1) bbase[NB] = s[t];   // == E
}

// ---------- K4: hp = fp16( (x @ W1) * dis[n] ) — 2x2 blocked, float4 LDS ----------
__global__ __launch_bounds__(256) void xw1_kernel(const float* __restrict__ x,
                                                  const float* __restrict__ W1,
                                                  const float* __restrict__ dis,
                                                  __half* __restrict__ hp, int N) {
    __shared__ float xs[64 * 132];    // 64 node rows, stride 132 (16B-aligned, conflict-safe)
    __shared__ float wt[16 * 132];    // W1 transposed: wt[k][d]
    int t = threadIdx.x;
    int base = blockIdx.x * 64;
    for (int i = t; i < DIN * 16; i += 256) {
        int d = i >> 4, k = i & 15;
        wt[k * 132 + d] = W1[i];
    }
    int nrow = min(64, N - base);
    for (int i = t; i < 64 * 32; i += 256) {
        int r = i >> 5, c4 = i & 31;
        float4 v = make_float4(0.f, 0.f, 0.f, 0.f);
        if (r < nrow) v = *(const float4*)(x + (size_t)(base + r) * DIN + c4 * 4);
        *(float4*)(xs + r * 132 + c4 * 4) = v;
    }
    __syncthreads();
    int np = t >> 3;          // 0..31 node-pair
    int kp = t & 7;           // 0..7  k-pair
    int n0 = np * 2, k0 = kp * 2;
    const float4* xa = (const float4*)(xs + n0 * 132);
    const float4* xb = (const float4*)(xs + (n0 + 1) * 132);
    const float4* wa = (const float4*)(wt + k0 * 132);
    const float4* wb = (const float4*)(wt + (k0 + 1) * 132);
    float a00 = 0.f, a01 = 0.f, a10 = 0.f, a11 = 0.f;
    #pragma unroll 8
    for (int d4 = 0; d4 < 32; d4++) {
        float4 va = xa[d4], vb = xb[d4], u0 = wa[d4], u1 = wb[d4];
        a00 += va.x*u0.x + va.y*u0.y + va.z*u0.z + va.w*u0.w;
        a01 += va.x*u1.x + va.y*u1.y + va.z*u1.z + va.w*u1.w;
        a10 += vb.x*u0.x + vb.y*u0.y + vb.z*u0.z + vb.w*u0.w;
        a11 += vb.x*u1.x + vb.y*u1.y + vb.z*u1.z + vb.w*u1.w;
    }
    int n = base + n0;
    if (n < N) {
        float d = dis[n];
        hp[(size_t)n * 16 + k0 + 0] = __float2half(a00 * d);
        hp[(size_t)n * 16 + k0 + 1] = __float2half(a01 * d);
    }
    n++;
    if (n < N) {
        float d = dis[n];
        hp[(size_t)n * 16 + k0 + 0] = __float2half(a10 * d);
        hp[(size_t)n * 16 + k0 + 1] = __float2half(a11 * d);
    }
}

// ---------- K5: fused per-bucket counting sort + gather-1 + relu/b1/@W2/*dis ----------
__global__ __launch_bounds__(256) void bsg1_kernel(const int* __restrict__ sp,
                                                   const int* __restrict__ bbase,
                                                   const float* __restrict__ dis,
                                                   const __half2* __restrict__ hp2,
                                                   const float* __restrict__ b1,
                                                   const float* __restrict__ W2,
                                                   int* __restrict__ srt,
                                                   int* __restrict__ off,
                                                   float* __restrict__ gp, int N) {
    __shared__ int spk[CAP];
    __shared__ int ss[CAP];
    __shared__ int lcnt[BSIZE], lstart[BSIZE], lcur[BSIZE], sc[BSIZE];
    int b = blockIdx.x;
    int t = threadIdx.x;
    int base = bbase[b];
    int cntb = bbase[b + 1] - base;
    const int* src = sp + (size_t)b * CAP;
    if (t < BSIZE) { lcnt[t] = 0; lcur[t] = 0; }
    __syncthreads();
    for (int i = t; i < cntb; i += 256) {
        int v = src[i];
        spk[i] = v;
        atomicAdd(&lcnt[v >> 17], 1);
    }
    __syncthreads();
    int v = (t < BSIZE) ? lcnt[t] : 0;
    if (t < BSIZE) sc[t] = v;
    __syncthreads();
    for (int d = 1; d < BSIZE; d <<= 1) {
        int tmp = (t < BSIZE && t >= d) ? sc[t - d] : 0;
        __syncthreads();
        if (t < BSIZE) sc[t] += tmp;
        __syncthreads();
    }
    if (t < BSIZE) lstart[t] = sc[t] - v;
    __syncthreads();
    for (int i = t; i < cntb; i += 256) {
        int vv = spk[i];
        int lt = vv >> 17;
        int rk = atomicAdd(&lcur[lt], 1);
        ss[lstart[lt] + rk] = vv & 0x1FFFF;
    }
    __syncthreads();
    for (int i = t; i < cntb; i += 256) srt[base + i] = ss[i];
    if (t < BSIZE) {
        int gt = b * BSIZE + t;
        if (gt < N) off[gt] = base + lstart[t];
    }
    // gather + epilogue: 4 rounds of 32 targets x 8 lanes; 4-way ILP on edges
    int k2  = t & 7;
    int ltg = t >> 3;            // 0..31
    #pragma unroll
    for (int r4 = 0; r4 < 4; r4++) {
        int lt = r4 * 32 + ltg;
        int gt = b * BSIZE + lt;
        if (gt < N) {
            int j0 = lstart[lt];
            int j1 = j0 + lcnt[lt];
            float2 acc0 = __half22float2(hp2[(size_t)gt * 8 + k2]);  // self-loop
            float2 acc1 = make_float2(0.f, 0.f);
            float2 acc2 = make_float2(0.f, 0.f);
            float2 acc3 = make_float2(0.f, 0.f);
            int j = j0;
            for (; j + 3 < j1; j += 4) {
                int r0 = ss[j + 0], r1 = ss[j + 1], r2 = ss[j + 2], r3 = ss[j + 3];
                float2 h0 = __half22float2(hp2[(size_t)r0 * 8 + k2]);
                float2 h1 = __half22float2(hp2[(size_t)r1 * 8 + k2]);
                float2 h2 = __half22float2(hp2[(size_t)r2 * 8 + k2]);
                float2 h3 = __half22float2(hp2[(size_t)r3 * 8 + k2]);
                acc0.x += h0.x; acc0.y += h0.y;
                acc1.x += h1.x; acc1.y += h1.y;
                acc2.x += h2.x; acc2.y += h2.y;
                acc3.x += h3.x; acc3.y += h3.y;
            }
            for (; j < j1; j++) {
                int r = ss[j];
                float2 hv = __half22float2(hp2[(size_t)r * 8 + k2]);
                acc0.x += hv.x; acc0.y += hv.y;
            }
            float2 acc = make_float2(acc0.x + acc1.x + acc2.x + acc3.x,
                                     acc0.y + acc1.y + acc2.y + acc3.y);
            float d = dis[gt];
            int k0 = k2 * 2;
            float v0 = fmaxf(fmaf(acc.x, d, b1[k0 + 0]), 0.0f);
            float v1 = fmaxf(fmaf(acc.y, d, b1[k0 + 1]), 0.0f);
            float p0 = v0 * W2[k0 * 2 + 0] + v1 * W2[k0 * 2 + 2];
            float p1 = v0 * W2[k0 * 2 + 1] + v1 * W2[k0 * 2 + 3];
            p0 += __shfl_xor(p0, 1); p1 += __shfl_xor(p1, 1);
            p0 += __shfl_xor(p0, 2); p1 += __shfl_xor(p1, 2);
            p0 += __shfl_xor(p0, 4); p1 += __shfl_xor(p1, 4);
            if (k2 == 0) *(float2*)(gp + (size_t)gt * 2) = make_float2(p0 * d, p1 * d);
        }
    }
}

// ---------- K6: CSR gather-2 (4 lanes/target) + bias + log_softmax ----------
__global__ __launch_bounds__(256) void g2_kernel(const int* __restrict__ srt,
                                                 const int* __restrict__ off,
                                                 const float* __restrict__ dis,
                                                 const float* __restrict__ gp,
                                                 const float* __restrict__ b2,
                                                 float* __restrict__ out, int N, int E) {
    int t = blockIdx.x * 256 + threadIdx.x;
    int c    = t >> 2;
    int slot = t & 3;
    if (c >= N) return;
    int j0 = off[c];
    int j1 = (c == N - 1) ? E : off[c + 1];
    float a0 = 0.0f, a1v = 0.0f;
    for (int j = j0 + slot; j < j1; j += 4) {
        int r = srt[j];
        float2 gv = *(const float2*)(gp + (size_t)r * 2);
        a0  += gv.x;
        a1v += gv.y;
    }
    a0 += __shfl_xor(a0, 1); a1v += __shfl_xor(a1v, 1);
    a0 += __shfl_xor(a0, 2); a1v += __shfl_xor(a1v, 2);
    if (slot == 0) {
        float2 self = *(const float2*)(gp + (size_t)c * 2);
        float d = dis[c];
        float o0 = (a0  + self.x) * d + b2[0];
        float o1 = (a1v + self.y) * d + b2[1];
        float m = fmaxf(o0, o1);
        float lse = m + logf(expf(o0 - m) + expf(o1 - m));
        *(float2*)(out + (size_t)c * 2) = make_float2(o0 - lse, o1 - lse);
    }
}

extern "C" void kernel_launch(void* const* d_in, const int* in_sizes, int n_in,
                              void* d_out, int out_size, void* d_ws, size_t ws_size,
                              hipStream_t stream) {
    const float* x  = (const float*)d_in[0];
    const int*   ei = (const int*)d_in[1];
    const float* W1 = (const float*)d_in[2];
    const float* b1 = (const float*)d_in[3];
    const float* W2 = (const float*)d_in[4];
    const float* b2 = (const float*)d_in[5];
    float* out = (float*)d_out;

    const int N = in_sizes[0] / DIN;          // 100000
    const int E = in_sizes[1] / 2;            // 3200000
    const int* row = ei;                      // sources
    const int* col = ei + E;                  // targets
    const int NB = (N + BSIZE - 1) / BSIZE;   // 782

    // ws layout (4B units): cur[NBMAX] | bbase[NBMAX+1] | dis[N] | off[N] | srt[E] |
    //                       sp[NB*CAP] | hp(half)[16N] | gp[2N]   (~32 MB total)
    int*    cur   = (int*)d_ws;
    int*    bbase = cur + NBMAX;
    float*  dis   = (float*)(bbase + NBMAX + 1);
    int*    off   = (int*)(dis + N);
    int*    srt   = off + N;
    int*    sp    = srt + E;
    __half* hp    = (__half*)(sp + (size_t)NB * CAP);
    float*  gp    = (float*)(hp + (size_t)N * 16);

    init_kernel <<<(NB + 255) / 256, 256, 0, stream>>>(cur, NB);
    place_kernel<<<(E + CHUNK - 1) / CHUNK, 256, 0, stream>>>(row, col, cur, sp, E, NB);
    bdeg_kernel <<<NB, 256, 0, stream>>>(sp, cur, dis, N);
    bscan_kernel<<<1, 1024, 0, stream>>>(cur, bbase, NB);
    xw1_kernel  <<<(N + 63) / 64, 256, 0, stream>>>(x, W1, dis, hp, N);
    bsg1_kernel <<<NB, 256, 0, stream>>>(sp, bbase, dis, (const __half2*)hp, b1, W2, srt, off, gp, N);
    g2_kernel   <<<(int)(((size_t)N * 4 + 255) / 256), 256, 0, stream>>>(srt, off, dis, gp, b2, out, N, E);
}